// Round 3
// baseline (490.048 us; speedup 1.0000x reference)
//
#include <hip/hip_runtime.h>
#include <hip/hip_bf16.h>

// Problem constants
#define SEGS   8
#define DIM    768
#define NVIS   100
#define BATCH  64
#define LTOK   512
#define NCHK   8        // reduction chunks per sequence
#define TPC    64       // tokens per chunk (512/8)

// ws layout (float element offsets). ~13 MB now (no GEMM partials, no TMEAN).
#define OFF_PCAP  0                                   // [B][NCHK][S][D] caption chunk partials
#define OFF_PTRC  (OFF_PCAP + BATCH*NCHK*SEGS*DIM)    // [B][NCHK][S][D] trace chunk partials
#define OFF_PVIS  (OFF_PTRC + BATCH*NCHK*SEGS*DIM)    // [B][2][D] vision sums (chunks 0,1 only)
#define OFF_PCCNT (OFF_PVIS + BATCH*2*DIM)            // [B][NCHK][S] int caption chunk counts
#define OFF_PTCNT (OFF_PCCNT + BATCH*NCHK*SEGS)       // [B][NCHK][S] int trace chunk counts

// Evidence log: inputs f32 (r1 NaN sig), output f32 (r2 shuffle sig).
// r4: 3.5M global atomics = 93us gemm -> plain-store partials.
// r5: reduce 112us @ 15% occ latency-bound -> 2x grid + load batching -> 85us.
// r6: reduce 85us @ 26.7% occ -> col-half split + 8-deep batching: occ 46%,
//     dur UNCHANGED (85us, 1.5 TB/s HBM, 2.7 TB/s effective incl. L3 hits).
//     Occupancy-independent plateau => shared-path (L3/fabric) streaming limit;
//     stop touching reduce.
// r7: total 284 - reduce 85 = 199us downstream (3 kernels + gaps) vs ~35us
//     traffic model => fuse combine1+gemm+combine2 into ONE kernel:
//     64 gemm-role blocks (per-b trace fold in LDS + full-K 9x1536 GEMM,
//     thread=4cols) + 1536 caption-role blocks. 4 launches -> 2.
// r8: r7 bench died with "MI355X container failed twice" (infra, no compile/
//     pytest verdict). Source audit found no hang/fault mechanism (uniform
//     barriers, bounds OK, ws shrank). Resubmitting identical kernel.

// ---------------------------------------------------------------------------
// Segment-sum reduction -> plain-store chunk partials. (unchanged from r6)
// grid = 2048: [type(2)][batch(64)][chunk(8)][colhalf(2)], block = 192
// ---------------------------------------------------------------------------
__global__ __launch_bounds__(192) void reduce_kernel(
    const float* __restrict__ vt_feat,
    const int* __restrict__ vt_mask,
    const float* __restrict__ cap_feat,
    const int* __restrict__ cap_mask,
    float* __restrict__ ws)
{
    const int bid  = blockIdx.x;
    const int type = bid >> 10;         // 0 = caption, 1 = trace/vision
    const int b    = (bid >> 4) & 63;
    const int ck   = (bid >> 1) & 7;
    const int half = bid & 1;
    const int tid  = threadIdx.x;       // 0..191
    const int c0   = half * 384 + tid * 2;   // this thread's 2 columns

    __shared__ __align__(16) int msk[TPC];
    __shared__ int scnt[SEGS + 1];
    if (tid < SEGS + 1) scnt[tid] = 0;
    if (tid < TPC) {
        const int l = ck * TPC + tid;
        int m;
        if (type == 0) m = cap_mask[b * 513 + 1 + l];
        else           m = (l >= NVIS) ? vt_mask[b * 412 + (l - NVIS)] : 0;
        msk[tid] = m;
    }
    __syncthreads();
    if (half == 0 && tid < TPC) {       // counts only needed once per (type,b,ck)
        const int m = msk[tid]; if (m > 0) atomicAdd(&scnt[m], 1);
    }

    float acc[SEGS][2];
#pragma unroll
    for (int s = 0; s < SEGS; ++s) { acc[s][0] = 0.f; acc[s][1] = 0.f; }
    float vacc[2] = {0.f, 0.f};
    float tmp[2]  = {0.f, 0.f};
    int cur = 0;

    const float* __restrict__ feat = (type == 0) ? cap_feat : vt_feat;
    const size_t base = (size_t)b * LTOK * DIM + (size_t)c0;

    for (int j = 0; j < TPC; j += 8) {
        const float* p = feat + base + (size_t)(ck * TPC + j) * DIM;
        float2 v[8];
#pragma unroll
        for (int u = 0; u < 8; ++u)
            v[u] = *reinterpret_cast<const float2*>(p + (size_t)u * DIM);
        const int4 m4a = *reinterpret_cast<const int4*>(&msk[j]);
        const int4 m4b = *reinterpret_cast<const int4*>(&msk[j + 4]);
        const int mm[8] = {m4a.x, m4a.y, m4a.z, m4a.w,
                           m4b.x, m4b.y, m4b.z, m4b.w};
#pragma unroll
        for (int u = 0; u < 8; ++u) {
            const int l = ck * TPC + j + u;
            if (type == 1 && l < NVIS) {
                vacc[0] += v[u].x; vacc[1] += v[u].y;
            } else {
                const int m = __builtin_amdgcn_readfirstlane(mm[u]);
                if (m != cur) {
#pragma unroll
                    for (int s = 0; s < SEGS; ++s)
                        if (cur == s + 1) {
                            acc[s][0] += tmp[0]; acc[s][1] += tmp[1];
                        }
                    tmp[0] = 0.f; tmp[1] = 0.f;
                    cur = m;
                }
                tmp[0] += v[u].x; tmp[1] += v[u].y;
            }
        }
    }
#pragma unroll
    for (int s = 0; s < SEGS; ++s)
        if (cur == s + 1) {
            acc[s][0] += tmp[0]; acc[s][1] += tmp[1];
        }

    __syncthreads();   // counts complete

    float* __restrict__ pbase = ws + (type == 0 ? OFF_PCAP : OFF_PTRC)
                              + ((size_t)(b * NCHK + ck) * SEGS) * DIM + c0;
#pragma unroll
    for (int s = 0; s < SEGS; ++s) {
        *reinterpret_cast<float2*>(pbase + s * DIM) =
            make_float2(acc[s][0], acc[s][1]);
    }
    if (half == 0) {
        int* __restrict__ cbase = (int*)(ws + (type == 0 ? OFF_PCCNT : OFF_PTCNT))
                                + (b * NCHK + ck) * SEGS;
        if (tid < SEGS) cbase[tid] = scnt[tid + 1];
    }
    if (type == 1 && ck < 2) {   // vision tokens l<100 live in chunks 0,1
        *reinterpret_cast<float2*>(ws + OFF_PVIS + (size_t)(b * 2 + ck) * DIM + c0) =
            make_float2(vacc[0], vacc[1]);
    }
}

// ---------------------------------------------------------------------------
// Fused epilogue: ONE kernel replaces combine1 + gemm + combine2.
//
// Blocks [0, 64): gemm role, one block per batch b.
//   Phase 1: fold trace counts (8 ints/seg) into LDS.
//   Phase 2: fold PTRC chunk partials -> tmean[0..7][768] (pre-divided) and
//            PVIS -> tmean[8][768] (vision mean), all in LDS (27.6 KB).
//   Phase 3: full-K GEMM: thread = 4 output cols (192 active of 256).
//            out[s][d] = (sum_k tmean[s][k]*W[k][d]
//                       + sum_k tmean[8][k]*W[768+k][d] + bias[d]) * present_s
//            LDS tmean reads are wave-broadcast float4, amortized over 4 cols
//            -> VALU-bound (~144 FMA per 4-k group per thread).
// Blocks [64, 64+1536): caption role, i = (bid-64)*256+tid over 393216 elems;
//   fold PCAP + counts, divide, write caption output (== old combine1 branch).
// No cross-block deps: both roles read only reduce's partials.
// ---------------------------------------------------------------------------
__global__ __launch_bounds__(256) void fused_kernel(
    const float* __restrict__ W,
    const float* __restrict__ bias,
    const float* __restrict__ ws_c,
    float* __restrict__ out)
{
    const int bid = blockIdx.x;
    const int tid = threadIdx.x;
    const int HALF = BATCH * SEGS * DIM;   // 393216

    __shared__ __align__(16) float tmean[9][DIM];   // rows 0-7 trace, row 8 vision
    __shared__ int scnt[SEGS];

    if (bid < BATCH) {
        // ---------------- gemm role ----------------
        const int b = bid;
        if (tid < SEGS) {
            int c = 0;
#pragma unroll
            for (int ck = 0; ck < NCHK; ++ck)
                c += ((const int*)(ws_c + OFF_PTCNT))[(b * NCHK + ck) * SEGS + tid];
            scnt[tid] = c;
        }
        __syncthreads();

        // trace means (pre-divided, zero where absent)
        for (int idx = tid; idx < SEGS * DIM; idx += 256) {
            const int s = idx / DIM, k = idx % DIM;
            float sum = 0.f;
#pragma unroll
            for (int ck = 0; ck < NCHK; ++ck)
                sum += ws_c[OFF_PTRC + ((size_t)((b * NCHK + ck) * SEGS + s)) * DIM + k];
            const int c = scnt[s];
            tmean[s][k] = (c > 0) ? sum / (float)c : 0.f;
        }
        // vision mean
        for (int k = tid; k < DIM; k += 256) {
            tmean[8][k] = (ws_c[OFF_PVIS + (size_t)(b * 2 + 0) * DIM + k] +
                           ws_c[OFF_PVIS + (size_t)(b * 2 + 1) * DIM + k]) * (1.0f / (float)NVIS);
        }
        __syncthreads();

        if (tid < 192) {
            const int d0 = tid * 4;
            float acc[9][4];
#pragma unroll
            for (int r = 0; r < 9; ++r) { acc[r][0]=0.f; acc[r][1]=0.f; acc[r][2]=0.f; acc[r][3]=0.f; }

            for (int k = 0; k < DIM; k += 4) {
                float a[9][4];
#pragma unroll
                for (int r = 0; r < 9; ++r) {
                    const float4 t = *reinterpret_cast<const float4*>(&tmean[r][k]);
                    a[r][0] = t.x; a[r][1] = t.y; a[r][2] = t.z; a[r][3] = t.w;
                }
#pragma unroll
                for (int u = 0; u < 4; ++u) {
                    const float4 wt4 = *reinterpret_cast<const float4*>(&W[(size_t)(k + u) * DIM + d0]);
                    const float4 wb4 = *reinterpret_cast<const float4*>(&W[(size_t)(DIM + k + u) * DIM + d0]);
                    const float wt[4] = {wt4.x, wt4.y, wt4.z, wt4.w};
                    const float wb[4] = {wb4.x, wb4.y, wb4.z, wb4.w};
#pragma unroll
                    for (int r = 0; r < SEGS; ++r) {
#pragma unroll
                        for (int j = 0; j < 4; ++j) acc[r][j] += a[r][u] * wt[j];
                    }
#pragma unroll
                    for (int j = 0; j < 4; ++j) acc[8][j] += a[8][u] * wb[j];
                }
            }

            const float4 b4 = *reinterpret_cast<const float4*>(bias + d0);
            float* __restrict__ o = out + HALF + ((size_t)b * SEGS) * DIM + d0;
#pragma unroll
            for (int s = 0; s < SEGS; ++s) {
                float4 v = make_float4(0.f, 0.f, 0.f, 0.f);
                if (scnt[s] > 0)
                    v = make_float4(acc[s][0] + acc[8][0] + b4.x,
                                    acc[s][1] + acc[8][1] + b4.y,
                                    acc[s][2] + acc[8][2] + b4.z,
                                    acc[s][3] + acc[8][3] + b4.w);
                *reinterpret_cast<float4*>(o + s * DIM) = v;
            }
        }
    } else {
        // ---------------- caption role ----------------
        const int i = (bid - BATCH) * 256 + tid;   // exactly covers 393216
        const int b = i / (SEGS * DIM);
        const int r = i % (SEGS * DIM);
        const int s = r / DIM, d = r % DIM;
        float sum = 0.f; int c = 0;
#pragma unroll
        for (int ck = 0; ck < NCHK; ++ck) {
            sum += ws_c[OFF_PCAP + ((size_t)((b * NCHK + ck) * SEGS + s)) * DIM + d];
            c   += ((const int*)(ws_c + OFF_PCCNT))[(b * NCHK + ck) * SEGS + s];
        }
        out[i] = (c > 0) ? sum / (float)c : 0.f;
    }
}

extern "C" void kernel_launch(void* const* d_in, const int* in_sizes, int n_in,
                              void* d_out, int out_size, void* d_ws, size_t ws_size,
                              hipStream_t stream) {
    const float* vt_feat  = (const float*)d_in[0];
    const int*   vt_mask  = (const int*)d_in[1];
    const float* cap_feat = (const float*)d_in[2];
    const int*   cap_mask = (const int*)d_in[3];
    const float* W        = (const float*)d_in[4];
    const float* bias     = (const float*)d_in[5];
    float* out = (float*)d_out;
    float* ws = (float*)d_ws;

    // No memset: every ws slot is plain-stored before it is read.
    reduce_kernel<<<2048, 192, 0, stream>>>(vt_feat, vt_mask, cap_feat, cap_mask, ws);
    fused_kernel <<<BATCH + 1536, 256, 0, stream>>>(W, bias, ws, out);
}

// Round 4
// 281.211 us; speedup vs baseline: 1.7426x; 1.7426x over previous
//
#include <hip/hip_runtime.h>
#include <hip/hip_bf16.h>

// Problem constants
#define SEGS   8
#define DIM    768
#define NVIS   100
#define BATCH  64
#define LTOK   512
#define NCHK   8        // reduction chunks per sequence
#define TPC    64       // tokens per chunk (512/8)

// ws layout (float element offsets), ~27 MB (same budget as the r0-r6 layout).
#define OFF_PCAP  0                                   // [B][NCHK][S][D] caption chunk partials
#define OFF_PTRC  (OFF_PCAP + BATCH*NCHK*SEGS*DIM)    // [B][NCHK][S][D] trace chunk partials
#define OFF_PVIS  (OFF_PTRC + BATCH*NCHK*SEGS*DIM)    // [B][2][D] vision sums (chunks 0,1 only)
#define OFF_PCCNT (OFF_PVIS + BATCH*2*DIM)            // [B][NCHK][S] int caption chunk counts
#define OFF_PTCNT (OFF_PCCNT + BATCH*NCHK*SEGS)       // [B][NCHK][S] int trace chunk counts
#define OFF_TMEAN (OFF_PTCNT + BATCH*NCHK*SEGS)       // [B][9][D] trace means + vision mean (row 8)
#define OFF_TCNT  (OFF_TMEAN + BATCH*9*DIM)           // [B][S] int summed trace counts

// Evidence log: inputs f32 (r1 NaN sig), output f32 (r2 shuffle sig).
// r4: 3.5M global atomics = 93us gemm -> plain-store partials.
// r5: reduce 112us @ 15% occ latency-bound -> 2x grid + load batching -> 85us.
// r6: reduce 85us: occ 26.7->46% yet dur UNCHANGED (1.5 TB/s HBM, 2.7 TB/s
//     effective incl. L3) => shared-path streaming limit; stop touching reduce.
// r7/r9: fused combine1+gemm+combine2 with 64 gemm-role blocks = 267us @
//     2.8% occ / 2.5% VALU: 64-block serial GEMM tail, one block per batch,
//     ~0.75 waves/SIMD -> W-load latency unhidden. GEMM work is ~9us chip-wide;
//     it was starved of blocks. RULE: no <=64-block compute tails.
// r10: 3-kernel structure: reduce (unchanged) + combine1 (float4-vectorized,
//     816 blocks) + gemm2 (512 blocks: b x 8 col-chunks, full-K N-split,
//     thread=(col,khalf), LDS pair-reduce, bias+mask, direct out write).

// ---------------------------------------------------------------------------
// Segment-sum reduction -> plain-store chunk partials. (unchanged from r6)
// grid = 2048: [type(2)][batch(64)][chunk(8)][colhalf(2)], block = 192
// ---------------------------------------------------------------------------
__global__ __launch_bounds__(192) void reduce_kernel(
    const float* __restrict__ vt_feat,
    const int* __restrict__ vt_mask,
    const float* __restrict__ cap_feat,
    const int* __restrict__ cap_mask,
    float* __restrict__ ws)
{
    const int bid  = blockIdx.x;
    const int type = bid >> 10;         // 0 = caption, 1 = trace/vision
    const int b    = (bid >> 4) & 63;
    const int ck   = (bid >> 1) & 7;
    const int half = bid & 1;
    const int tid  = threadIdx.x;       // 0..191
    const int c0   = half * 384 + tid * 2;   // this thread's 2 columns

    __shared__ __align__(16) int msk[TPC];
    __shared__ int scnt[SEGS + 1];
    if (tid < SEGS + 1) scnt[tid] = 0;
    if (tid < TPC) {
        const int l = ck * TPC + tid;
        int m;
        if (type == 0) m = cap_mask[b * 513 + 1 + l];
        else           m = (l >= NVIS) ? vt_mask[b * 412 + (l - NVIS)] : 0;
        msk[tid] = m;
    }
    __syncthreads();
    if (half == 0 && tid < TPC) {       // counts only needed once per (type,b,ck)
        const int m = msk[tid]; if (m > 0) atomicAdd(&scnt[m], 1);
    }

    float acc[SEGS][2];
#pragma unroll
    for (int s = 0; s < SEGS; ++s) { acc[s][0] = 0.f; acc[s][1] = 0.f; }
    float vacc[2] = {0.f, 0.f};
    float tmp[2]  = {0.f, 0.f};
    int cur = 0;

    const float* __restrict__ feat = (type == 0) ? cap_feat : vt_feat;
    const size_t base = (size_t)b * LTOK * DIM + (size_t)c0;

    for (int j = 0; j < TPC; j += 8) {
        const float* p = feat + base + (size_t)(ck * TPC + j) * DIM;
        float2 v[8];
#pragma unroll
        for (int u = 0; u < 8; ++u)
            v[u] = *reinterpret_cast<const float2*>(p + (size_t)u * DIM);
        const int4 m4a = *reinterpret_cast<const int4*>(&msk[j]);
        const int4 m4b = *reinterpret_cast<const int4*>(&msk[j + 4]);
        const int mm[8] = {m4a.x, m4a.y, m4a.z, m4a.w,
                           m4b.x, m4b.y, m4b.z, m4b.w};
#pragma unroll
        for (int u = 0; u < 8; ++u) {
            const int l = ck * TPC + j + u;
            if (type == 1 && l < NVIS) {
                vacc[0] += v[u].x; vacc[1] += v[u].y;
            } else {
                const int m = __builtin_amdgcn_readfirstlane(mm[u]);
                if (m != cur) {
#pragma unroll
                    for (int s = 0; s < SEGS; ++s)
                        if (cur == s + 1) {
                            acc[s][0] += tmp[0]; acc[s][1] += tmp[1];
                        }
                    tmp[0] = 0.f; tmp[1] = 0.f;
                    cur = m;
                }
                tmp[0] += v[u].x; tmp[1] += v[u].y;
            }
        }
    }
#pragma unroll
    for (int s = 0; s < SEGS; ++s)
        if (cur == s + 1) {
            acc[s][0] += tmp[0]; acc[s][1] += tmp[1];
        }

    __syncthreads();   // counts complete

    float* __restrict__ pbase = ws + (type == 0 ? OFF_PCAP : OFF_PTRC)
                              + ((size_t)(b * NCHK + ck) * SEGS) * DIM + c0;
#pragma unroll
    for (int s = 0; s < SEGS; ++s) {
        *reinterpret_cast<float2*>(pbase + s * DIM) =
            make_float2(acc[s][0], acc[s][1]);
    }
    if (half == 0) {
        int* __restrict__ cbase = (int*)(ws + (type == 0 ? OFF_PCCNT : OFF_PTCNT))
                                + (b * NCHK + ck) * SEGS;
        if (tid < SEGS) cbase[tid] = scnt[tid + 1];
    }
    if (type == 1 && ck < 2) {   // vision tokens l<100 live in chunks 0,1
        *reinterpret_cast<float2*>(ws + OFF_PVIS + (size_t)(b * 2 + ck) * DIM + c0) =
            make_float2(vacc[0], vacc[1]);
    }
}

// ---------------------------------------------------------------------------
// Combine 1 (float4): fold chunk partials. Caption OUTPUT directly, trace
// means (pre-divided) + vision mean -> TMEAN, trace counts -> TCNT.
// grid = 816 x 256 over 208896 float4 elements (2*98304 cap/trace + 12288 vis).
// ---------------------------------------------------------------------------
__global__ __launch_bounds__(256) void combine1_kernel(
    const float* __restrict__ ws_c, float* __restrict__ ws,
    float* __restrict__ out)
{
    const int i = blockIdx.x * 256 + threadIdx.x;   // float4 index
    const int N1 = BATCH * SEGS * DIM / 4;          // 98304
    if (i < N1) {
        const int b  = i / 1536;                    // SEGS*DIM/4
        const int r  = i % 1536;
        const int s  = r / 192;                     // DIM/4
        const int d4 = (r % 192) * 4;
        float4 sum = make_float4(0.f, 0.f, 0.f, 0.f); int c = 0;
#pragma unroll
        for (int ck = 0; ck < NCHK; ++ck) {
            const float4 v = *reinterpret_cast<const float4*>(
                ws_c + OFF_PCAP + ((size_t)((b * NCHK + ck) * SEGS + s)) * DIM + d4);
            sum.x += v.x; sum.y += v.y; sum.z += v.z; sum.w += v.w;
            c += ((const int*)(ws_c + OFF_PCCNT))[(b * NCHK + ck) * SEGS + s];
        }
        float4 o = make_float4(0.f, 0.f, 0.f, 0.f);
        if (c > 0) {
            const float fc = (float)c;
            o = make_float4(sum.x / fc, sum.y / fc, sum.z / fc, sum.w / fc);
        }
        reinterpret_cast<float4*>(out)[i] = o;
    } else if (i < 2 * N1) {
        const int j  = i - N1;
        const int b  = j / 1536;
        const int r  = j % 1536;
        const int s  = r / 192;
        const int d4 = (r % 192) * 4;
        float4 sum = make_float4(0.f, 0.f, 0.f, 0.f); int c = 0;
#pragma unroll
        for (int ck = 0; ck < NCHK; ++ck) {
            const float4 v = *reinterpret_cast<const float4*>(
                ws_c + OFF_PTRC + ((size_t)((b * NCHK + ck) * SEGS + s)) * DIM + d4);
            sum.x += v.x; sum.y += v.y; sum.z += v.z; sum.w += v.w;
            c += ((const int*)(ws_c + OFF_PTCNT))[(b * NCHK + ck) * SEGS + s];
        }
        float4 m = make_float4(0.f, 0.f, 0.f, 0.f);
        if (c > 0) {
            const float fc = (float)c;
            m = make_float4(sum.x / fc, sum.y / fc, sum.z / fc, sum.w / fc);
        }
        *reinterpret_cast<float4*>(ws + OFF_TMEAN + ((size_t)(b * 9 + s)) * DIM + d4) = m;
        if (d4 == 0) ((int*)(ws + OFF_TCNT))[b * SEGS + s] = c;
    } else {
        const int j  = i - 2 * N1;                  // [0, 12288)
        const int b  = j / 192;
        const int d4 = (j % 192) * 4;
        const float4 v0 = *reinterpret_cast<const float4*>(
            ws_c + OFF_PVIS + (size_t)(b * 2 + 0) * DIM + d4);
        const float4 v1 = *reinterpret_cast<const float4*>(
            ws_c + OFF_PVIS + (size_t)(b * 2 + 1) * DIM + d4);
        const float sc = 1.0f / (float)NVIS;
        *reinterpret_cast<float4*>(ws + OFF_TMEAN + ((size_t)(b * 9 + 8)) * DIM + d4) =
            make_float4((v0.x + v1.x) * sc, (v0.y + v1.y) * sc,
                        (v0.z + v1.z) * sc, (v0.w + v1.w) * sc);
    }
}

// ---------------------------------------------------------------------------
// gemm2: replaces gemm + combine2. Full-K, N-split: grid = 512
// ([batch 64] x [8 col-chunks of 96]), block = 192; thread = (col, k-half).
// TMEAN[b] (9x768) staged in LDS; per-thread 9 accumulators over its K=384
// half; pair-reduce via LDS; + bias, presence mask, direct vt output write.
// No partials ws round-trip, no 4th kernel. 2 blocks/CU -> 6 waves/CU.
// ---------------------------------------------------------------------------
__global__ __launch_bounds__(192) void gemm2_kernel(
    const float* __restrict__ W,
    const float* __restrict__ bias,
    const float* __restrict__ ws_c,
    float* __restrict__ out)
{
    const int b   = blockIdx.x >> 3;
    const int nc  = blockIdx.x & 7;
    const int n0  = nc * 96;
    const int tid = threadIdx.x;      // 0..191
    const int col = tid >> 1;         // 0..95
    const int kh  = tid & 1;          // k-half
    const int d   = n0 + col;

    __shared__ __align__(16) float tm[9 * DIM];   // 27.6 KB
    __shared__ float red[192][9];                 // 6.9 KB pair-reduce buffer

    // Cooperative TMEAN load: 1728 float4, coalesced.
    for (int idx = tid; idx < 9 * DIM / 4; idx += 192) {
        reinterpret_cast<float4*>(tm)[idx] =
            reinterpret_cast<const float4*>(ws_c + OFF_TMEAN + (size_t)b * 9 * DIM)[idx];
    }
    __syncthreads();

    float acc[9];
#pragma unroll
    for (int r = 0; r < 9; ++r) acc[r] = 0.f;

    const int k0 = kh * 384;
    const float* __restrict__ Wt = W + (size_t)k0 * DIM + d;
    const float* __restrict__ Wb = W + (size_t)(DIM + k0) * DIM + d;

    for (int k = 0; k < 384; k += 4) {
        // 8 independent W loads batched before use (even/odd lanes: 2 coalesced runs)
        float wt[4], wb[4];
#pragma unroll
        for (int u = 0; u < 4; ++u) {
            wt[u] = Wt[(size_t)(k + u) * DIM];
            wb[u] = Wb[(size_t)(k + u) * DIM];
        }
        float a[9][4];
#pragma unroll
        for (int r = 0; r < 9; ++r) {
            // Two broadcast groups per wave (even/odd lanes), 2-way max = free.
            const float4 t = *reinterpret_cast<const float4*>(&tm[r * DIM + k0 + k]);
            a[r][0] = t.x; a[r][1] = t.y; a[r][2] = t.z; a[r][3] = t.w;
        }
#pragma unroll
        for (int u = 0; u < 4; ++u) {
#pragma unroll
            for (int r = 0; r < SEGS; ++r) acc[r] += a[r][u] * wt[u];
            acc[8] += a[8][u] * wb[u];
        }
    }

    // Pair-reduce across the two k-halves (banks: stride 9 is coprime to 32 -> 2-way max).
#pragma unroll
    for (int r = 0; r < 9; ++r) red[tid][r] = acc[r];
    __syncthreads();
    if (kh == 0) {
        float accT[9];
#pragma unroll
        for (int r = 0; r < 9; ++r) accT[r] = acc[r] + red[tid + 1][r];
        const float bs = bias[d];
        float* __restrict__ o = out + (size_t)BATCH * SEGS * DIM
                              + ((size_t)b * SEGS) * DIM + d;
#pragma unroll
        for (int s = 0; s < SEGS; ++s) {
            const int c = ((const int*)(ws_c + OFF_TCNT))[b * SEGS + s];
            o[(size_t)s * DIM] = (c > 0) ? (accT[s] + accT[8] + bs) : 0.f;
        }
    }
}

extern "C" void kernel_launch(void* const* d_in, const int* in_sizes, int n_in,
                              void* d_out, int out_size, void* d_ws, size_t ws_size,
                              hipStream_t stream) {
    const float* vt_feat  = (const float*)d_in[0];
    const int*   vt_mask  = (const int*)d_in[1];
    const float* cap_feat = (const float*)d_in[2];
    const int*   cap_mask = (const int*)d_in[3];
    const float* W        = (const float*)d_in[4];
    const float* bias     = (const float*)d_in[5];
    float* out = (float*)d_out;
    float* ws = (float*)d_ws;

    // No memset: every ws slot is plain-stored before it is read.
    reduce_kernel  <<<2048, 192, 0, stream>>>(vt_feat, vt_mask, cap_feat, cap_mask, ws);
    combine1_kernel<<<816, 256, 0, stream>>>(ws, ws, out);
    gemm2_kernel   <<<512, 192, 0, stream>>>(W, bias, ws, out);
}

// Round 5
// 259.473 us; speedup vs baseline: 1.8886x; 1.0838x over previous
//
#include <hip/hip_runtime.h>
#include <hip/hip_bf16.h>

// Problem constants
#define SEGS   8
#define DIM    768
#define NVIS   100
#define BATCH  64
#define LTOK   512
#define NCHK   8        // reduction chunks per sequence
#define TPC    64       // tokens per chunk (512/8)

// ws layout (float element offsets), ~27 MB (same budget as the r0-r6 layout).
#define OFF_PCAP  0                                   // [B][NCHK][S][D] caption chunk partials
#define OFF_PTRC  (OFF_PCAP + BATCH*NCHK*SEGS*DIM)    // [B][NCHK][S][D] trace chunk partials
#define OFF_PVIS  (OFF_PTRC + BATCH*NCHK*SEGS*DIM)    // [B][2][D] vision sums (chunks 0,1 only)
#define OFF_PCCNT (OFF_PVIS + BATCH*2*DIM)            // [B][NCHK][S] int caption chunk counts
#define OFF_PTCNT (OFF_PCCNT + BATCH*NCHK*SEGS)       // [B][NCHK][S] int trace chunk counts
#define OFF_TMEAN (OFF_PTCNT + BATCH*NCHK*SEGS)       // [B][9][D] trace means + vision mean (row 8)
#define OFF_TCNT  (OFF_TMEAN + BATCH*9*DIM)           // [B][S] int summed trace counts

// Evidence log: inputs f32 (r1 NaN sig), output f32 (r2 shuffle sig).
// r4: 3.5M global atomics = 93us gemm -> plain-store partials.
// r5: reduce 112us @ 15% occ latency-bound -> 2x grid + load batching -> 85us.
// r6: reduce 85us: occ 26.7->46% yet dur UNCHANGED => shared-path streaming
//     plateau (~2.7 TB/s effective incl. L3); stop touching reduce.
// r7/r9: 64-block gemm tail = 267us @ 2.8% occ. RULE: no <=64-block tails.
// r10: 3-kernel (reduce + f4-combine1 + N-split gemm2): 281us — downstream
//     restructure moved nothing. Accounting with r3's DIRECT fused
//     measurement (490 = 85 + 267 + X => X ~ 138us) closes: total 281 =
//     reduce 84 + downstream ~59 + FIXED ~138us harness overhead
//     (reset/poison dispatches; ~33-dispatch iteration period).
// r11: attack downstream slack: gemm2 inner loop was scalar W loads (768/thr)
//     + 864 ds_read_b128/thr (1-col amortization, ~26us chip LDS time).
//     Rewrite: thread = (4 cols x K-eighth): f4 W loads, 4x fewer ds_reads,
//     kq-padded tm[9][8][100] (conflict-free broadcast), 8-way LDS reduce.

// ---------------------------------------------------------------------------
// Segment-sum reduction -> plain-store chunk partials. (unchanged from r6)
// grid = 2048: [type(2)][batch(64)][chunk(8)][colhalf(2)], block = 192
// ---------------------------------------------------------------------------
__global__ __launch_bounds__(192) void reduce_kernel(
    const float* __restrict__ vt_feat,
    const int* __restrict__ vt_mask,
    const float* __restrict__ cap_feat,
    const int* __restrict__ cap_mask,
    float* __restrict__ ws)
{
    const int bid  = blockIdx.x;
    const int type = bid >> 10;         // 0 = caption, 1 = trace/vision
    const int b    = (bid >> 4) & 63;
    const int ck   = (bid >> 1) & 7;
    const int half = bid & 1;
    const int tid  = threadIdx.x;       // 0..191
    const int c0   = half * 384 + tid * 2;   // this thread's 2 columns

    __shared__ __align__(16) int msk[TPC];
    __shared__ int scnt[SEGS + 1];
    if (tid < SEGS + 1) scnt[tid] = 0;
    if (tid < TPC) {
        const int l = ck * TPC + tid;
        int m;
        if (type == 0) m = cap_mask[b * 513 + 1 + l];
        else           m = (l >= NVIS) ? vt_mask[b * 412 + (l - NVIS)] : 0;
        msk[tid] = m;
    }
    __syncthreads();
    if (half == 0 && tid < TPC) {       // counts only needed once per (type,b,ck)
        const int m = msk[tid]; if (m > 0) atomicAdd(&scnt[m], 1);
    }

    float acc[SEGS][2];
#pragma unroll
    for (int s = 0; s < SEGS; ++s) { acc[s][0] = 0.f; acc[s][1] = 0.f; }
    float vacc[2] = {0.f, 0.f};
    float tmp[2]  = {0.f, 0.f};
    int cur = 0;

    const float* __restrict__ feat = (type == 0) ? cap_feat : vt_feat;
    const size_t base = (size_t)b * LTOK * DIM + (size_t)c0;

    for (int j = 0; j < TPC; j += 8) {
        const float* p = feat + base + (size_t)(ck * TPC + j) * DIM;
        float2 v[8];
#pragma unroll
        for (int u = 0; u < 8; ++u)
            v[u] = *reinterpret_cast<const float2*>(p + (size_t)u * DIM);
        const int4 m4a = *reinterpret_cast<const int4*>(&msk[j]);
        const int4 m4b = *reinterpret_cast<const int4*>(&msk[j + 4]);
        const int mm[8] = {m4a.x, m4a.y, m4a.z, m4a.w,
                           m4b.x, m4b.y, m4b.z, m4b.w};
#pragma unroll
        for (int u = 0; u < 8; ++u) {
            const int l = ck * TPC + j + u;
            if (type == 1 && l < NVIS) {
                vacc[0] += v[u].x; vacc[1] += v[u].y;
            } else {
                const int m = __builtin_amdgcn_readfirstlane(mm[u]);
                if (m != cur) {
#pragma unroll
                    for (int s = 0; s < SEGS; ++s)
                        if (cur == s + 1) {
                            acc[s][0] += tmp[0]; acc[s][1] += tmp[1];
                        }
                    tmp[0] = 0.f; tmp[1] = 0.f;
                    cur = m;
                }
                tmp[0] += v[u].x; tmp[1] += v[u].y;
            }
        }
    }
#pragma unroll
    for (int s = 0; s < SEGS; ++s)
        if (cur == s + 1) {
            acc[s][0] += tmp[0]; acc[s][1] += tmp[1];
        }

    __syncthreads();   // counts complete

    float* __restrict__ pbase = ws + (type == 0 ? OFF_PCAP : OFF_PTRC)
                              + ((size_t)(b * NCHK + ck) * SEGS) * DIM + c0;
#pragma unroll
    for (int s = 0; s < SEGS; ++s) {
        *reinterpret_cast<float2*>(pbase + s * DIM) =
            make_float2(acc[s][0], acc[s][1]);
    }
    if (half == 0) {
        int* __restrict__ cbase = (int*)(ws + (type == 0 ? OFF_PCCNT : OFF_PTCNT))
                                + (b * NCHK + ck) * SEGS;
        if (tid < SEGS) cbase[tid] = scnt[tid + 1];
    }
    if (type == 1 && ck < 2) {   // vision tokens l<100 live in chunks 0,1
        *reinterpret_cast<float2*>(ws + OFF_PVIS + (size_t)(b * 2 + ck) * DIM + c0) =
            make_float2(vacc[0], vacc[1]);
    }
}

// ---------------------------------------------------------------------------
// Combine 1 (float4): fold chunk partials. Caption OUTPUT directly, trace
// means (pre-divided) + vision mean -> TMEAN, trace counts -> TCNT.
// grid = 816 x 256 over 208896 float4 elements. (unchanged from r10)
// ---------------------------------------------------------------------------
__global__ __launch_bounds__(256) void combine1_kernel(
    const float* __restrict__ ws_c, float* __restrict__ ws,
    float* __restrict__ out)
{
    const int i = blockIdx.x * 256 + threadIdx.x;   // float4 index
    const int N1 = BATCH * SEGS * DIM / 4;          // 98304
    if (i < N1) {
        const int b  = i / 1536;                    // SEGS*DIM/4
        const int r  = i % 1536;
        const int s  = r / 192;                     // DIM/4
        const int d4 = (r % 192) * 4;
        float4 sum = make_float4(0.f, 0.f, 0.f, 0.f); int c = 0;
#pragma unroll
        for (int ck = 0; ck < NCHK; ++ck) {
            const float4 v = *reinterpret_cast<const float4*>(
                ws_c + OFF_PCAP + ((size_t)((b * NCHK + ck) * SEGS + s)) * DIM + d4);
            sum.x += v.x; sum.y += v.y; sum.z += v.z; sum.w += v.w;
            c += ((const int*)(ws_c + OFF_PCCNT))[(b * NCHK + ck) * SEGS + s];
        }
        float4 o = make_float4(0.f, 0.f, 0.f, 0.f);
        if (c > 0) {
            const float fc = (float)c;
            o = make_float4(sum.x / fc, sum.y / fc, sum.z / fc, sum.w / fc);
        }
        reinterpret_cast<float4*>(out)[i] = o;
    } else if (i < 2 * N1) {
        const int j  = i - N1;
        const int b  = j / 1536;
        const int r  = j % 1536;
        const int s  = r / 192;
        const int d4 = (r % 192) * 4;
        float4 sum = make_float4(0.f, 0.f, 0.f, 0.f); int c = 0;
#pragma unroll
        for (int ck = 0; ck < NCHK; ++ck) {
            const float4 v = *reinterpret_cast<const float4*>(
                ws_c + OFF_PTRC + ((size_t)((b * NCHK + ck) * SEGS + s)) * DIM + d4);
            sum.x += v.x; sum.y += v.y; sum.z += v.z; sum.w += v.w;
            c += ((const int*)(ws_c + OFF_PTCNT))[(b * NCHK + ck) * SEGS + s];
        }
        float4 m = make_float4(0.f, 0.f, 0.f, 0.f);
        if (c > 0) {
            const float fc = (float)c;
            m = make_float4(sum.x / fc, sum.y / fc, sum.z / fc, sum.w / fc);
        }
        *reinterpret_cast<float4*>(ws + OFF_TMEAN + ((size_t)(b * 9 + s)) * DIM + d4) = m;
        if (d4 == 0) ((int*)(ws + OFF_TCNT))[b * SEGS + s] = c;
    } else {
        const int j  = i - 2 * N1;                  // [0, 12288)
        const int b  = j / 192;
        const int d4 = (j % 192) * 4;
        const float4 v0 = *reinterpret_cast<const float4*>(
            ws_c + OFF_PVIS + (size_t)(b * 2 + 0) * DIM + d4);
        const float4 v1 = *reinterpret_cast<const float4*>(
            ws_c + OFF_PVIS + (size_t)(b * 2 + 1) * DIM + d4);
        const float sc = 1.0f / (float)NVIS;
        *reinterpret_cast<float4*>(ws + OFF_TMEAN + ((size_t)(b * 9 + 8)) * DIM + d4) =
            make_float4((v0.x + v1.x) * sc, (v0.y + v1.y) * sc,
                        (v0.z + v1.z) * sc, (v0.w + v1.w) * sc);
    }
}

// ---------------------------------------------------------------------------
// gemm2 v2: full-K, N-split. grid = 512 ([batch 64] x [8 col-chunks of 96]),
// block = 192; thread = (col-group of 4, K-eighth): cg = tid%24, kq = tid/24.
//   - W loads are float4 (4 cols), 8 per 4-k group.
//   - tmean staged as tm[9][8][100] (kq-padded): per-(r,k) reads are
//     broadcast within a kq-group; the 3 kq-groups per wave hit banks
//     4*kq apart (stride 100 % 32 = 4) -> conflict-free.
//   - each ds_read_b128 feeds 16 FMAs (4 k x 4 cols): 216 reads/thread
//     vs 864 in r10's version.
//   - 8-way reduce over kq via LDS, + bias, presence mask, direct out write.
// LDS = 28.8 KB tm + 27.6 KB red = 56.4 KB -> 2 blocks/CU (grid gives 2).
// ---------------------------------------------------------------------------
__global__ __launch_bounds__(192) void gemm2_kernel(
    const float* __restrict__ W,
    const float* __restrict__ bias,
    const float* __restrict__ ws_c,
    float* __restrict__ out)
{
    const int b   = blockIdx.x >> 3;
    const int nc  = blockIdx.x & 7;
    const int n0  = nc * 96;
    const int tid = threadIdx.x;      // 0..191
    const int cg  = tid % 24;         // col group: 4 cols
    const int kq  = tid / 24;         // K-eighth: 96 k's
    const int d0  = n0 + cg * 4;

    __shared__ __align__(16) float tm[9 * 8 * 100];    // kq-padded tmean
    __shared__ __align__(16) float red[192 * 9 * 4];   // per-thread acc[9] f4

    // Stage TMEAN[b] (9x768, pre-divided) into padded layout.
    // Natural f4 index idx = r*192 + kq_*24 + kk4  ->  tm[(r*8+kq_)*100 + kk4*4]
    for (int idx = tid; idx < 9 * DIM / 4; idx += 192) {
        const int r   = idx / 192;
        const int rem = idx % 192;
        const int kq_ = rem / 24;
        const int kk4 = rem % 24;
        const float4 v = reinterpret_cast<const float4*>(
            ws_c + OFF_TMEAN + (size_t)b * 9 * DIM)[idx];
        *reinterpret_cast<float4*>(&tm[(r * 8 + kq_) * 100 + kk4 * 4]) = v;
    }
    __syncthreads();

    float acc[9][4];
#pragma unroll
    for (int r = 0; r < 9; ++r) { acc[r][0]=0.f; acc[r][1]=0.f; acc[r][2]=0.f; acc[r][3]=0.f; }

    const float* __restrict__ Wt = W + (size_t)(kq * 96) * DIM + d0;
    const float* __restrict__ Wb = W + (size_t)(DIM + kq * 96) * DIM + d0;

    for (int kk = 0; kk < 96; kk += 4) {
        // 8 independent float4 W loads batched before use.
        float4 wt[4], wb[4];
#pragma unroll
        for (int u = 0; u < 4; ++u) {
            wt[u] = *reinterpret_cast<const float4*>(Wt + (size_t)(kk + u) * DIM);
            wb[u] = *reinterpret_cast<const float4*>(Wb + (size_t)(kk + u) * DIM);
        }
        float a[9][4];
#pragma unroll
        for (int r = 0; r < 9; ++r) {
            const float4 t = *reinterpret_cast<const float4*>(&tm[(r * 8 + kq) * 100 + kk]);
            a[r][0] = t.x; a[r][1] = t.y; a[r][2] = t.z; a[r][3] = t.w;
        }
#pragma unroll
        for (int u = 0; u < 4; ++u) {
            const float t4[4] = {wt[u].x, wt[u].y, wt[u].z, wt[u].w};
            const float b4[4] = {wb[u].x, wb[u].y, wb[u].z, wb[u].w};
#pragma unroll
            for (int r = 0; r < SEGS; ++r) {
#pragma unroll
                for (int j = 0; j < 4; ++j) acc[r][j] += a[r][u] * t4[j];
            }
#pragma unroll
            for (int j = 0; j < 4; ++j) acc[8][j] += a[8][u] * b4[j];
        }
    }

    // Dump acc to LDS: red[(tid*9 + r)] as float4 (lane stride 36 dwords -> spread).
#pragma unroll
    for (int r = 0; r < 9; ++r)
        *reinterpret_cast<float4*>(&red[(tid * 9 + r) * 4]) =
            make_float4(acc[r][0], acc[r][1], acc[r][2], acc[r][3]);
    __syncthreads();

    // Final: thread t = (cg2, s): 24 x 8 = 192. 8-way fold over kq + vision row.
    {
        const int cg2 = tid >> 3;        // 0..23
        const int s   = tid & 7;         // 0..7
        float4 sumS = make_float4(0.f, 0.f, 0.f, 0.f);
        float4 sumV = make_float4(0.f, 0.f, 0.f, 0.f);
#pragma unroll
        for (int q = 0; q < 8; ++q) {
            const int base = (q * 24 + cg2) * 9;
            const float4 vS = *reinterpret_cast<const float4*>(&red[(base + s) * 4]);
            const float4 vV = *reinterpret_cast<const float4*>(&red[(base + 8) * 4]);
            sumS.x += vS.x; sumS.y += vS.y; sumS.z += vS.z; sumS.w += vS.w;
            sumV.x += vV.x; sumV.y += vV.y; sumV.z += vV.z; sumV.w += vV.w;
        }
        const int dd = n0 + cg2 * 4;
        const int c  = ((const int*)(ws_c + OFF_TCNT))[b * SEGS + s];
        float4 o = make_float4(0.f, 0.f, 0.f, 0.f);
        if (c > 0) {
            const float4 bb = *reinterpret_cast<const float4*>(bias + dd);
            o = make_float4(sumS.x + sumV.x + bb.x, sumS.y + sumV.y + bb.y,
                            sumS.z + sumV.z + bb.z, sumS.w + sumV.w + bb.w);
        }
        *reinterpret_cast<float4*>(out + (size_t)BATCH * SEGS * DIM
                                   + ((size_t)(b * SEGS + s)) * DIM + dd) = o;
    }
}

extern "C" void kernel_launch(void* const* d_in, const int* in_sizes, int n_in,
                              void* d_out, int out_size, void* d_ws, size_t ws_size,
                              hipStream_t stream) {
    const float* vt_feat  = (const float*)d_in[0];
    const int*   vt_mask  = (const int*)d_in[1];
    const float* cap_feat = (const float*)d_in[2];
    const int*   cap_mask = (const int*)d_in[3];
    const float* W        = (const float*)d_in[4];
    const float* bias     = (const float*)d_in[5];
    float* out = (float*)d_out;
    float* ws = (float*)d_ws;

    // No memset: every ws slot is plain-stored before it is read.
    reduce_kernel  <<<2048, 192, 0, stream>>>(vt_feat, vt_mask, cap_feat, cap_mask, ws);
    combine1_kernel<<<816, 256, 0, stream>>>(ws, ws, out);
    gemm2_kernel   <<<512, 192, 0, stream>>>(W, bias, ws, out);
}